// Round 7
// baseline (581.243 us; speedup 1.0000x reference)
//
#include <hip/hip_runtime.h>
#include <hip/hip_bf16.h>

// GAT layer, N=8192, F_in=512, F_out=128.
// exp(leaky_relu(s1+s2)) = pos ? exp(s1)exp(s2) : exp(.2 s1)exp(.2 s2)
// r7: three structural fixes driven by r6 counters (231us kMain, all pipes idle):
//  - adj touched ONCE by a barrier-free coalesced ballot pass (mask = 8MB).
//  - kCompute reads mask in MFMA A-fragment lane layout (lane owns row l&15);
//    one u32 word = 32 cols, preloaded per 512-col stripe. NO LDS, NO barriers.
//  - h pre-swizzled into fragment "blob": B-operand loads are lane-contiguous
//    1KB dwordx4 (r6 scattered 16 lines/inst).
// Floor (uncontrollable): ~160us 1GiB ws poison + ~85us input restore.

typedef __attribute__((ext_vector_type(4))) float f32x4;
typedef __attribute__((ext_vector_type(8))) short s16x8;

#define N_NODES 8192
#define F_IN 512
#define F_OUT 128

static __device__ __forceinline__ short f2bf(float f) {
  __hip_bfloat16 h = __float2bfloat16(f);
  return __builtin_bit_cast(short, h);
}

// ------- kMask: adj(int32 NxN) -> bitmask; 256 cols (4 words) per task ----
__global__ __launch_bounds__(256) void kMask(const int* __restrict__ adj,
    unsigned long long* __restrict__ mask) {
  const int nwaves = gridDim.x * 4;
  int wid = blockIdx.x * 4 + (threadIdx.x >> 6);
  int lane = threadIdx.x & 63;
  const int ntasks = N_NODES * (N_NODES / 256);   // 262,144 wave-tasks
  for (int task = wid; task < ntasks; task += nwaves) {
    int row = task >> 5;
    int cg = task & 31;
    const int* p = adj + (size_t)row * N_NODES + cg * 256 + lane;
    int v0 = p[0], v1 = p[64], v2 = p[128], v3 = p[192];
    unsigned long long b0 = __ballot(v0 != 0);
    unsigned long long b1 = __ballot(v1 != 0);
    unsigned long long b2 = __ballot(v2 != 0);
    unsigned long long b3 = __ballot(v3 != 0);
    if (lane == 0) {
      unsigned long long* q = mask + (size_t)row * (N_NODES / 64) + cg * 4;
      ulonglong2 w0; w0.x = b0; w0.y = b1;
      ulonglong2 w1; w1.x = b2; w1.y = b3;
      *(ulonglong2*)(q) = w0;
      *(ulonglong2*)(q + 2) = w1;
    }
  }
}

// ---------------- kA: {W->WT bf16} ∪ {wa = W@a1, W@a2} ----------------
__global__ __launch_bounds__(256) void kA(const float* __restrict__ W,
    const float* __restrict__ a, unsigned short* __restrict__ WT,
    float* __restrict__ wa) {
  int b = blockIdx.x;
  if (b < 256) {
    int idx = b * 256 + threadIdx.x;
    int k = idx >> 7, f = idx & 127;
    WT[(size_t)f * F_IN + k] = (unsigned short)f2bf(W[idx]);
  } else {
    int k = (b - 256) * 256 + threadIdx.x;
    if (k < F_IN) {
      const float* Wr = W + (size_t)k * F_OUT;
      float d1 = 0.f, d2 = 0.f;
#pragma unroll 8
      for (int f = 0; f < F_OUT; f += 4) {
        f32x4 w  = *(const f32x4*)(Wr + f);
        f32x4 a1 = *(const f32x4*)(a + f);
        f32x4 a2 = *(const f32x4*)(a + F_OUT + f);
        d1 += w[0] * a1[0] + w[1] * a1[1] + w[2] * a1[2] + w[3] * a1[3];
        d2 += w[0] * a2[0] + w[1] * a2[1] + w[2] * a2[2] + w[3] * a2[3];
      }
      wa[k] = d1;
      wa[F_IN + k] = d2;
    }
  }
}

// ------- kStage: {h GEMM -> fragment blob} ∪ {rowdat/pE tables} -----------
// blob element: value h[ft*16 + (l&15)][ct*32 + (l>>4)*8 + e] stored at
// shorts[((ft*256 + ct)*64 + l)*8 + e]  -> consumer loads are lane-contiguous.
__global__ __launch_bounds__(256) void kStage(const float* __restrict__ X,
    const float* __restrict__ wa, const unsigned short* __restrict__ WT,
    f32x4* __restrict__ rowdat, unsigned* __restrict__ pE,
    unsigned short* __restrict__ blob) {
  int b = blockIdx.x;
  int wave = threadIdx.x >> 6, lane = threadIdx.x & 63;

  if (b < 1024) {
    int lrow = lane & 15, grp = lane >> 4;
    int tile = b * 4 + wave;                       // 4096 tiles
    int fb = tile & 7;
    int nb = tile >> 3;
    const unsigned short* Ar = WT + (size_t)(fb * 16 + lrow) * F_IN + grp * 8;
    const float* Br = X + (size_t)(nb * 16 + lrow) * F_IN + grp * 8;

    f32x4 acc = (f32x4)(0.0f);
#pragma unroll
    for (int k0 = 0; k0 < F_IN; k0 += 32) {
      s16x8 af = *(const s16x8*)(Ar + k0);
      f32x4 b0 = *(const f32x4*)(Br + k0);
      f32x4 b1 = *(const f32x4*)(Br + k0 + 4);
      s16x8 bf;
#pragma unroll
      for (int e = 0; e < 4; e++) { bf[e] = f2bf(b0[e]); bf[e + 4] = f2bf(b1[e]); }
      acc = __builtin_amdgcn_mfma_f32_16x16x32_bf16(af, bf, acc, 0, 0, 0);
    }
    // acc[r] = h[f = fb*16+grp*4+r][c = nb*16+lrow]; scatter into blob layout
    int cc = (nb & 1) * 16 + lrow;
    size_t bl = ((size_t)(fb * 256 + (nb >> 1)) * 64 + (cc >> 3) * 16 + grp * 4);
#pragma unroll
    for (int r = 0; r < 4; r++)
      blob[(bl + r) * 8 + (lrow & 7)] = (unsigned short)f2bf(acc[r]);
  } else {
    // ---- per-row s1,s2 = X@wa -> rowdat, pE ----
    int i = (b - 1024) * 4 + wave;
    const float* Xr = X + (size_t)i * F_IN + lane * 8;
    f32x4 x0 = ((const f32x4*)Xr)[0];
    f32x4 x1 = ((const f32x4*)Xr)[1];
    f32x4 w10 = ((const f32x4*)(wa + lane * 8))[0];
    f32x4 w11 = ((const f32x4*)(wa + lane * 8))[1];
    f32x4 w20 = ((const f32x4*)(wa + F_IN + lane * 8))[0];
    f32x4 w21 = ((const f32x4*)(wa + F_IN + lane * 8))[1];
    float d1 = 0.f, d2 = 0.f;
#pragma unroll
    for (int e = 0; e < 4; e++) {
      d1 += x0[e] * w10[e] + x1[e] * w11[e];
      d2 += x0[e] * w20[e] + x1[e] * w21[e];
    }
#pragma unroll
    for (int m = 1; m < 64; m <<= 1) {
      d1 += __shfl_xor(d1, m, 64);
      d2 += __shfl_xor(d2, m, 64);
    }
    if (lane == 0) {
      float s1 = d1, s2 = d2;
      f32x4 rd;
      rd[0] = expf(s1);          // E1
      rd[1] = expf(0.2f * s1);   // E1s
      rd[2] = expf(-s1);         // T1: pos <=> E2 > T1
      rd[3] = 0.f;
      rowdat[i] = rd;
      unsigned e2  = (unsigned)(unsigned short)f2bf(expf(s2));
      unsigned e2s = (unsigned)(unsigned short)f2bf(expf(0.2f * s2));
      pE[i] = (e2s << 16) | e2;
    }
  }
}

// ------- kCompute: barrier-free masked P@h; lane owns row l&15 -------------
// Block: 32 rows x 4096 cols. Wave w: rowtile w&1, featgroup w>>1 (64 feats).
// Per 32-col chunk: P built in registers directly in A-fragment layout from
// mask bits + pE; B loaded lane-contiguous from blob; 4 MFMA.
__global__ __launch_bounds__(256, 2) void kCompute(
    const unsigned* __restrict__ mask32, const unsigned short* __restrict__ blob,
    const f32x4* __restrict__ rowdat, const unsigned* __restrict__ pE,
    float* __restrict__ accws, float* __restrict__ denws) {
  int wave = threadIdx.x >> 6, lane = threadIdx.x & 63;
  int lrow = lane & 15, grp = lane >> 4;
  int rb = blockIdx.x >> 1;                 // row-group of 32
  int js = blockIdx.x & 1;                  // col half
  int rowtile = wave & 1, fg = wave >> 1;
  int row = rb * 32 + rowtile * 16 + lrow;  // P row this lane computes

  f32x4 rd = rowdat[row];
  float E1 = rd[0], E1s = rd[1], T1 = rd[2];

  f32x4 acc[4];
#pragma unroll
  for (int nt = 0; nt < 4; nt++) acc[nt] = (f32x4)(0.0f);
  float dsum = 0.f;

  const unsigned* mrow = mask32 + (size_t)row * (N_NODES / 32) + js * 128;

  for (int o = 0; o < 8; o++) {
    uint4 mm[4];
    const uint4* mp = (const uint4*)(mrow + o * 16);
#pragma unroll
    for (int q = 0; q < 4; q++) mm[q] = mp[q];

#pragma unroll
    for (int c = 0; c < 16; c++) {
      int ct = js * 128 + o * 16 + c;       // global 32-col chunk id
      int j0 = ct * 32 + grp * 8;
      unsigned w = mm[c >> 2][c & 3];
      uint4 P0 = *(const uint4*)(pE + j0);
      uint4 P1 = *(const uint4*)(pE + j0 + 4);
      s16x8 af;
#define PROCE(pw, e)                                                  \
      {                                                               \
        unsigned pu = (pw);                                           \
        float E2  = __builtin_bit_cast(float, pu << 16);              \
        float E2s = __builtin_bit_cast(float, pu & 0xffff0000u);      \
        float sel = (E2 > T1) ? E1 * E2 : E1s * E2s;                  \
        float p = ((w >> (grp * 8 + (e))) & 1u) ? sel : 0.f;          \
        dsum += p;                                                    \
        af[e] = f2bf(p);                                              \
      }
      PROCE(P0.x, 0) PROCE(P0.y, 1) PROCE(P0.z, 2) PROCE(P0.w, 3)
      PROCE(P1.x, 4) PROCE(P1.y, 5) PROCE(P1.z, 6) PROCE(P1.w, 7)
#undef PROCE
#pragma unroll
      for (int nt = 0; nt < 4; nt++) {
        s16x8 bf = *(const s16x8*)(blob +
            (((size_t)(fg * 4 + nt) * 256 + ct) * 64 + lane) * 8);
        acc[nt] = __builtin_amdgcn_mfma_f32_16x16x32_bf16(af, bf, acc[nt], 0, 0, 0);
      }
    }
  }

  // den[row]: reduce over the 4 grp groups (lanes l, l^16, l^32, l^48)
  dsum += __shfl_xor(dsum, 16, 64);
  dsum += __shfl_xor(dsum, 32, 64);
  if (fg == 0 && lane < 16)
    denws[js * N_NODES + rb * 32 + rowtile * 16 + lane] = dsum;

  // acc store: D row within rowtile = grp*4+r, feat = fg*64 + nt*16 + lrow
#pragma unroll
  for (int nt = 0; nt < 4; nt++)
#pragma unroll
    for (int r = 0; r < 4; r++)
      accws[((size_t)js * N_NODES + rb * 32 + rowtile * 16 + grp * 4 + r) * F_OUT +
            fg * 64 + nt * 16 + lrow] = acc[nt][r];
}

// ---------------- kD: combine 2 slices, normalize, elu (float4) -----------
__global__ void kD(const float* __restrict__ accws,
                   const float* __restrict__ denws, float* __restrict__ out) {
  int idx4 = blockIdx.x * 256 + threadIdx.x;    // 262144 float4s
  int i = idx4 >> 5;
  const int S4 = N_NODES * F_OUT / 4;
  f32x4 s = ((const f32x4*)accws)[idx4] + ((const f32x4*)accws)[idx4 + S4];
  float d = denws[i] + denws[i + N_NODES];
  f32x4 v = s / d;
#pragma unroll
  for (int e = 0; e < 4; e++) v[e] = v[e] > 0.f ? v[e] : expm1f(v[e]);
  ((f32x4*)out)[idx4] = v;
}

extern "C" void kernel_launch(void* const* d_in, const int* in_sizes, int n_in,
                              void* d_out, int out_size, void* d_ws, size_t ws_size,
                              hipStream_t stream) {
  const float* X   = (const float*)d_in[0];
  const int*   adj = (const int*)d_in[1];
  const float* W   = (const float*)d_in[2];
  const float* a   = (const float*)d_in[3];
  float* out = (float*)d_out;

  char* ws = (char*)d_ws;
  size_t off = 0;
  unsigned short* WT = (unsigned short*)(ws + off); off += (size_t)F_OUT * F_IN * 2;
  unsigned short* blob = (unsigned short*)(ws + off); off += (size_t)F_OUT * N_NODES * 2;
  f32x4* rowdat = (f32x4*)(ws + off); off += (size_t)N_NODES * 16;
  unsigned* pE = (unsigned*)(ws + off); off += (size_t)N_NODES * 4;
  float* wa = (float*)(ws + off); off += (size_t)2 * F_IN * 4;
  unsigned long long* mask = (unsigned long long*)(ws + off);
  off += (size_t)N_NODES * (N_NODES / 64) * 8;   // 8 MB
  float* accws = (float*)(ws + off); off += (size_t)2 * N_NODES * F_OUT * 4;
  float* denws = (float*)(ws + off); off += (size_t)2 * N_NODES * 4;
  (void)in_sizes; (void)n_in; (void)out_size; (void)ws_size;

  kMask<<<2048, 256, 0, stream>>>(adj, mask);
  kA<<<258, 256, 0, stream>>>(W, a, WT, wa);
  kStage<<<3072, 256, 0, stream>>>(X, wa, WT, rowdat, pE, blob);
  kCompute<<<(N_NODES / 32) * 2, 256, 0, stream>>>((const unsigned*)mask, blob,
                                                   rowdat, pE, accws, denws);
  kD<<<(N_NODES * F_OUT) / 4 / 256, 256, 0, stream>>>(accws, denws, out);
}

// Round 8
// 486.363 us; speedup vs baseline: 1.1951x; 1.1951x over previous
//
#include <hip/hip_runtime.h>
#include <hip/hip_bf16.h>

// GAT layer, N=8192, F_in=512, F_out=128.
// exp(leaky_relu(s1+s2)) = pos ? exp(s1)exp(s2) : exp(.2 s1)exp(.2 s2)
// r8: kCompute rescheduled per r7 counters (stall-bound: VALUBusy 20%, Occ 22%):
//  - wave = 16 rows x 1024 cols x ALL 128 feats (no P duplication; block's 4
//    waves read identical blob bytes -> L1 reuse 4x)
//  - js=8 -> 1024 blocks = 4/CU, launch_bounds(256,4) -> ~16 waves/CU TLP
//  - masks per-o (L1-hot), pE broadcast loads, no barriers, rolled o-loop
// Floor (uncontrollable): ~160us 1GiB ws poison + ~85us input restore.

typedef __attribute__((ext_vector_type(4))) float f32x4;
typedef __attribute__((ext_vector_type(8))) short s16x8;

#define N_NODES 8192
#define F_IN 512
#define F_OUT 128
#define JS 8

static __device__ __forceinline__ short f2bf(float f) {
  __hip_bfloat16 h = __float2bfloat16(f);
  return __builtin_bit_cast(short, h);
}

// ------- kMask: adj(int32 NxN) -> bitmask; 256 cols (4 words) per task ----
__global__ __launch_bounds__(256) void kMask(const int* __restrict__ adj,
    unsigned long long* __restrict__ mask) {
  const int nwaves = gridDim.x * 4;
  int wid = blockIdx.x * 4 + (threadIdx.x >> 6);
  int lane = threadIdx.x & 63;
  const int ntasks = N_NODES * (N_NODES / 256);   // 262,144 wave-tasks
  for (int task = wid; task < ntasks; task += nwaves) {
    int row = task >> 5;
    int cg = task & 31;
    const int* p = adj + (size_t)row * N_NODES + cg * 256 + lane;
    int v0 = p[0], v1 = p[64], v2 = p[128], v3 = p[192];
    unsigned long long b0 = __ballot(v0 != 0);
    unsigned long long b1 = __ballot(v1 != 0);
    unsigned long long b2 = __ballot(v2 != 0);
    unsigned long long b3 = __ballot(v3 != 0);
    if (lane == 0) {
      unsigned long long* q = mask + (size_t)row * (N_NODES / 64) + cg * 4;
      ulonglong2 w0; w0.x = b0; w0.y = b1;
      ulonglong2 w1; w1.x = b2; w1.y = b3;
      *(ulonglong2*)(q) = w0;
      *(ulonglong2*)(q + 2) = w1;
    }
  }
}

// ---------------- kA: {W->WT bf16} ∪ {wa = W@a1, W@a2} ----------------
__global__ __launch_bounds__(256) void kA(const float* __restrict__ W,
    const float* __restrict__ a, unsigned short* __restrict__ WT,
    float* __restrict__ wa) {
  int b = blockIdx.x;
  if (b < 256) {
    int idx = b * 256 + threadIdx.x;
    int k = idx >> 7, f = idx & 127;
    WT[(size_t)f * F_IN + k] = (unsigned short)f2bf(W[idx]);
  } else {
    int k = (b - 256) * 256 + threadIdx.x;
    if (k < F_IN) {
      const float* Wr = W + (size_t)k * F_OUT;
      float d1 = 0.f, d2 = 0.f;
#pragma unroll 8
      for (int f = 0; f < F_OUT; f += 4) {
        f32x4 w  = *(const f32x4*)(Wr + f);
        f32x4 a1 = *(const f32x4*)(a + f);
        f32x4 a2 = *(const f32x4*)(a + F_OUT + f);
        d1 += w[0] * a1[0] + w[1] * a1[1] + w[2] * a1[2] + w[3] * a1[3];
        d2 += w[0] * a2[0] + w[1] * a2[1] + w[2] * a2[2] + w[3] * a2[3];
      }
      wa[k] = d1;
      wa[F_IN + k] = d2;
    }
  }
}

// ------- kStage: {h GEMM -> fragment blob} ∪ {rowdat/pE tables} -----------
// blob element: value h[ft*16 + (l&15)][ct*32 + (l>>4)*8 + e] stored at
// shorts[((ft*256 + ct)*64 + l)*8 + e]  -> consumer loads are lane-contiguous.
__global__ __launch_bounds__(256) void kStage(const float* __restrict__ X,
    const float* __restrict__ wa, const unsigned short* __restrict__ WT,
    f32x4* __restrict__ rowdat, unsigned* __restrict__ pE,
    unsigned short* __restrict__ blob) {
  int b = blockIdx.x;
  int wave = threadIdx.x >> 6, lane = threadIdx.x & 63;

  if (b < 1024) {
    int lrow = lane & 15, grp = lane >> 4;
    int tile = b * 4 + wave;                       // 4096 tiles
    int fb = tile & 7;
    int nb = tile >> 3;
    const unsigned short* Ar = WT + (size_t)(fb * 16 + lrow) * F_IN + grp * 8;
    const float* Br = X + (size_t)(nb * 16 + lrow) * F_IN + grp * 8;

    f32x4 acc = (f32x4)(0.0f);
#pragma unroll
    for (int k0 = 0; k0 < F_IN; k0 += 32) {
      s16x8 af = *(const s16x8*)(Ar + k0);
      f32x4 b0 = *(const f32x4*)(Br + k0);
      f32x4 b1 = *(const f32x4*)(Br + k0 + 4);
      s16x8 bf;
#pragma unroll
      for (int e = 0; e < 4; e++) { bf[e] = f2bf(b0[e]); bf[e + 4] = f2bf(b1[e]); }
      acc = __builtin_amdgcn_mfma_f32_16x16x32_bf16(af, bf, acc, 0, 0, 0);
    }
    // acc[r] = h[f = fb*16+grp*4+r][c = nb*16+lrow]; scatter into blob layout
    int cc = (nb & 1) * 16 + lrow;
    size_t bl = ((size_t)(fb * 256 + (nb >> 1)) * 64 + (cc >> 3) * 16 + grp * 4);
#pragma unroll
    for (int r = 0; r < 4; r++)
      blob[(bl + r) * 8 + (lrow & 7)] = (unsigned short)f2bf(acc[r]);
  } else {
    // ---- per-row s1,s2 = X@wa -> rowdat, pE ----
    int i = (b - 1024) * 4 + wave;
    const float* Xr = X + (size_t)i * F_IN + lane * 8;
    f32x4 x0 = ((const f32x4*)Xr)[0];
    f32x4 x1 = ((const f32x4*)Xr)[1];
    f32x4 w10 = ((const f32x4*)(wa + lane * 8))[0];
    f32x4 w11 = ((const f32x4*)(wa + lane * 8))[1];
    f32x4 w20 = ((const f32x4*)(wa + F_IN + lane * 8))[0];
    f32x4 w21 = ((const f32x4*)(wa + F_IN + lane * 8))[1];
    float d1 = 0.f, d2 = 0.f;
#pragma unroll
    for (int e = 0; e < 4; e++) {
      d1 += x0[e] * w10[e] + x1[e] * w11[e];
      d2 += x0[e] * w20[e] + x1[e] * w21[e];
    }
#pragma unroll
    for (int m = 1; m < 64; m <<= 1) {
      d1 += __shfl_xor(d1, m, 64);
      d2 += __shfl_xor(d2, m, 64);
    }
    if (lane == 0) {
      float s1 = d1, s2 = d2;
      f32x4 rd;
      rd[0] = expf(s1);          // E1
      rd[1] = expf(0.2f * s1);   // E1s
      rd[2] = expf(-s1);         // T1: pos <=> E2 > T1
      rd[3] = 0.f;
      rowdat[i] = rd;
      unsigned e2  = (unsigned)(unsigned short)f2bf(expf(s2));
      unsigned e2s = (unsigned)(unsigned short)f2bf(expf(0.2f * s2));
      pE[i] = (e2s << 16) | e2;
    }
  }
}

// ------- kCompute: wave = 16 rows x 1024 cols x 128 feats; no barriers ----
__global__ __launch_bounds__(256, 4) void kCompute(
    const unsigned* __restrict__ mask32, const unsigned short* __restrict__ blob,
    const f32x4* __restrict__ rowdat, const unsigned* __restrict__ pE,
    float* __restrict__ accws, float* __restrict__ denws) {
  int wave = threadIdx.x >> 6, lane = threadIdx.x & 63;
  int lrow = lane & 15, grp = lane >> 4;
  int rb = blockIdx.x >> 3;                 // 0..127 (64-row groups)
  int js = blockIdx.x & 7;                  // col eighth (32 chunks)
  int row = rb * 64 + wave * 16 + lrow;     // P row this lane computes

  f32x4 rd = rowdat[row];
  float E1 = rd[0], E1s = rd[1], T1 = rd[2];

  f32x4 acc[8];
#pragma unroll
  for (int nt = 0; nt < 8; nt++) acc[nt] = (f32x4)(0.0f);
  float dsum = 0.f;

  const unsigned* mrow = mask32 + (size_t)row * (N_NODES / 32) + js * 32;

  for (int o = 0; o < 4; o++) {             // rolled: 8 chunks per iter
    uint4 cm0 = *(const uint4*)(mrow + o * 8);
    uint4 cm1 = *(const uint4*)(mrow + o * 8 + 4);

#pragma unroll
    for (int c = 0; c < 8; c++) {
      int ct = js * 32 + o * 8 + c;         // global 32-col chunk id
      int j0 = ct * 32 + grp * 8;
      unsigned w = (c < 4) ? cm0[c] : cm1[c - 4];
      unsigned b8 = (w >> (grp * 8)) & 0xffu;
      uint4 P0 = *(const uint4*)(pE + j0);
      uint4 P1 = *(const uint4*)(pE + j0 + 4);
      s16x8 af;
#define PROCE(pw, e)                                                  \
      {                                                               \
        unsigned pu = (pw);                                           \
        float E2  = __builtin_bit_cast(float, pu << 16);              \
        float E2s = __builtin_bit_cast(float, pu & 0xffff0000u);      \
        float sel = (E2 > T1) ? E1 * E2 : E1s * E2s;                  \
        float p = ((b8 >> (e)) & 1u) ? sel : 0.f;                     \
        dsum += p;                                                    \
        af[e] = f2bf(p);                                              \
      }
      PROCE(P0.x, 0) PROCE(P0.y, 1) PROCE(P0.z, 2) PROCE(P0.w, 3)
      PROCE(P1.x, 4) PROCE(P1.y, 5) PROCE(P1.z, 6) PROCE(P1.w, 7)
#undef PROCE
#pragma unroll
      for (int nt = 0; nt < 8; nt++) {
        s16x8 bf = *(const s16x8*)(blob +
            (((size_t)nt * 256 + ct) * 64 + lane) * 8);
        acc[nt] = __builtin_amdgcn_mfma_f32_16x16x32_bf16(af, bf, acc[nt], 0, 0, 0);
      }
    }
  }

  // den[row]: reduce over the 4 grp groups (lanes l, l^16, l^32, l^48)
  dsum += __shfl_xor(dsum, 16, 64);
  dsum += __shfl_xor(dsum, 32, 64);
  if (lane < 16)
    denws[js * N_NODES + rb * 64 + wave * 16 + lane] = dsum;

  // acc store: D row within rowtile = grp*4+r, feat = nt*16 + lrow
#pragma unroll
  for (int nt = 0; nt < 8; nt++)
#pragma unroll
    for (int r = 0; r < 4; r++)
      accws[((size_t)js * N_NODES + rb * 64 + wave * 16 + grp * 4 + r) * F_OUT +
            nt * 16 + lrow] = acc[nt][r];
}

// ---------------- kD: combine 8 slices, normalize, elu (float4) -----------
__global__ void kD(const float* __restrict__ accws,
                   const float* __restrict__ denws, float* __restrict__ out) {
  int idx4 = blockIdx.x * 256 + threadIdx.x;    // 262144 float4s
  int i = idx4 >> 5;
  const int S4 = N_NODES * F_OUT / 4;
  f32x4 s = (f32x4)(0.0f);
  float d = 0.f;
#pragma unroll
  for (int q = 0; q < JS; q++) {
    s += ((const f32x4*)accws)[idx4 + (size_t)q * S4];
    d += denws[i + q * N_NODES];
  }
  f32x4 v = s / d;
#pragma unroll
  for (int e = 0; e < 4; e++) v[e] = v[e] > 0.f ? v[e] : expm1f(v[e]);
  ((f32x4*)out)[idx4] = v;
}

extern "C" void kernel_launch(void* const* d_in, const int* in_sizes, int n_in,
                              void* d_out, int out_size, void* d_ws, size_t ws_size,
                              hipStream_t stream) {
  const float* X   = (const float*)d_in[0];
  const int*   adj = (const int*)d_in[1];
  const float* W   = (const float*)d_in[2];
  const float* a   = (const float*)d_in[3];
  float* out = (float*)d_out;

  char* ws = (char*)d_ws;
  size_t off = 0;
  unsigned short* WT = (unsigned short*)(ws + off); off += (size_t)F_OUT * F_IN * 2;
  unsigned short* blob = (unsigned short*)(ws + off); off += (size_t)F_OUT * N_NODES * 2;
  f32x4* rowdat = (f32x4*)(ws + off); off += (size_t)N_NODES * 16;
  unsigned* pE = (unsigned*)(ws + off); off += (size_t)N_NODES * 4;
  float* wa = (float*)(ws + off); off += (size_t)2 * F_IN * 4;
  unsigned long long* mask = (unsigned long long*)(ws + off);
  off += (size_t)N_NODES * (N_NODES / 64) * 8;   // 8 MB
  float* accws = (float*)(ws + off); off += (size_t)JS * N_NODES * F_OUT * 4; // 32MB
  float* denws = (float*)(ws + off); off += (size_t)JS * N_NODES * 4;
  (void)in_sizes; (void)n_in; (void)out_size; (void)ws_size;

  kMask<<<2048, 256, 0, stream>>>(adj, mask);
  kA<<<258, 256, 0, stream>>>(W, a, WT, wa);
  kStage<<<3072, 256, 0, stream>>>(X, wa, WT, rowdat, pE, blob);
  kCompute<<<(N_NODES / 64) * JS, 256, 0, stream>>>((const unsigned*)mask, blob,
                                                    rowdat, pE, accws, denws);
  kD<<<(N_NODES * F_OUT) / 4 / 256, 256, 0, stream>>>(accws, denws, out);
}

// Round 12
// 478.865 us; speedup vs baseline: 1.2138x; 1.0157x over previous
//
#include <hip/hip_runtime.h>
#include <hip/hip_bf16.h>

// GAT layer, N=8192, F_in=512, F_out=128.
// exp(leaky_relu(s1+s2)) = pos ? exp(s1)exp(s2) : exp(.2 s1)exp(.2 s2)
// r12 = r11 resubmit (r11 hit a GPU-acquisition timeout, never ran).
// (a) kPrep fuses {adj->mask stream ∥ h-GEMM->blob ∥ rowdat/pE} with
// mask blocks first (BW stream hides the compute roles); (b) kCompute has an
// explicit 2-stage register pipeline (prefetch chunk c+1 pE/blob during chunk
// c PROCE+MFMA), wave = 16 rows x 1024 cols x 64 feats, VGPR<=128 @ (256,4).
// Floor (uncontrollable): ~160us 1GiB ws poison + ~85us input restore.

typedef __attribute__((ext_vector_type(4))) float f32x4;
typedef __attribute__((ext_vector_type(8))) short s16x8;

#define N_NODES 8192
#define F_IN 512
#define F_OUT 128
#define JS 8

static __device__ __forceinline__ short f2bf(float f) {
  __hip_bfloat16 h = __float2bfloat16(f);
  return __builtin_bit_cast(short, h);
}

// ---------------- kA: {W->WT bf16} ∪ {wa = W@a1, W@a2} ----------------
__global__ __launch_bounds__(256) void kA(const float* __restrict__ W,
    const float* __restrict__ a, unsigned short* __restrict__ WT,
    float* __restrict__ wa) {
  int b = blockIdx.x;
  if (b < 256) {
    int idx = b * 256 + threadIdx.x;
    int k = idx >> 7, f = idx & 127;
    WT[(size_t)f * F_IN + k] = (unsigned short)f2bf(W[idx]);
  } else {
    int k = (b - 256) * 256 + threadIdx.x;
    if (k < F_IN) {
      const float* Wr = W + (size_t)k * F_OUT;
      float d1 = 0.f, d2 = 0.f;
#pragma unroll 8
      for (int f = 0; f < F_OUT; f += 4) {
        f32x4 w  = *(const f32x4*)(Wr + f);
        f32x4 a1 = *(const f32x4*)(a + f);
        f32x4 a2 = *(const f32x4*)(a + F_OUT + f);
        d1 += w[0] * a1[0] + w[1] * a1[1] + w[2] * a1[2] + w[3] * a1[3];
        d2 += w[0] * a2[0] + w[1] * a2[1] + w[2] * a2[2] + w[3] * a2[3];
      }
      wa[k] = d1;
      wa[F_IN + k] = d2;
    }
  }
}

// ---- kPrep: {adj->mask (first, BW)} ∪ {h GEMM -> blob} ∪ {rowdat/pE} ------
// blob element: h[ft*16 + (l&15)][ct*32 + (l>>4)*8 + e] at
// shorts[((ft*256 + ct)*64 + l)*8 + e]  -> consumer loads lane-contiguous.
__global__ __launch_bounds__(256) void kPrep(const int* __restrict__ adj,
    unsigned long long* __restrict__ mask, const float* __restrict__ X,
    const float* __restrict__ wa, const unsigned short* __restrict__ WT,
    f32x4* __restrict__ rowdat, unsigned* __restrict__ pE,
    unsigned short* __restrict__ blob) {
  int b = blockIdx.x;
  int wave = threadIdx.x >> 6, lane = threadIdx.x & 63;

  if (b < 4096) {
    // ---- adj -> bitmask; 256 cols (4 ballots + 32B store) per task ----
    const int nwaves = 4096 * 4;
    int wid = b * 4 + wave;
    const int ntasks = N_NODES * (N_NODES / 256);   // 262,144
    for (int task = wid; task < ntasks; task += nwaves) {
      int row = task >> 5;
      int cg = task & 31;
      const int* p = adj + (size_t)row * N_NODES + cg * 256 + lane;
      int v0 = p[0], v1 = p[64], v2 = p[128], v3 = p[192];
      unsigned long long b0 = __ballot(v0 != 0);
      unsigned long long b1 = __ballot(v1 != 0);
      unsigned long long b2 = __ballot(v2 != 0);
      unsigned long long b3 = __ballot(v3 != 0);
      if (lane == 0) {
        unsigned long long* q = mask + (size_t)row * (N_NODES / 64) + cg * 4;
        ulonglong2 w0; w0.x = b0; w0.y = b1;
        ulonglong2 w1; w1.x = b2; w1.y = b3;
        *(ulonglong2*)(q) = w0;
        *(ulonglong2*)(q + 2) = w1;
      }
    }
  } else if (b < 5120) {
    // ---- h GEMM tile -> blob (fragment layout), inline f32->bf16 B ----
    int lrow = lane & 15, grp = lane >> 4;
    int tile = (b - 4096) * 4 + wave;              // 4096 tiles
    int fb = tile & 7;
    int nb = tile >> 3;
    const unsigned short* Ar = WT + (size_t)(fb * 16 + lrow) * F_IN + grp * 8;
    const float* Br = X + (size_t)(nb * 16 + lrow) * F_IN + grp * 8;

    f32x4 acc = (f32x4)(0.0f);
#pragma unroll
    for (int k0 = 0; k0 < F_IN; k0 += 32) {
      s16x8 af = *(const s16x8*)(Ar + k0);
      f32x4 b0 = *(const f32x4*)(Br + k0);
      f32x4 b1 = *(const f32x4*)(Br + k0 + 4);
      s16x8 bf;
#pragma unroll
      for (int e = 0; e < 4; e++) { bf[e] = f2bf(b0[e]); bf[e + 4] = f2bf(b1[e]); }
      acc = __builtin_amdgcn_mfma_f32_16x16x32_bf16(af, bf, acc, 0, 0, 0);
    }
    // acc[r] = h[f = fb*16+grp*4+r][c = nb*16+lrow] -> blob scatter
    int cc = (nb & 1) * 16 + lrow;
    size_t bl = ((size_t)(fb * 256 + (nb >> 1)) * 64 + (cc >> 3) * 16 + grp * 4);
#pragma unroll
    for (int r = 0; r < 4; r++)
      blob[(bl + r) * 8 + (lrow & 7)] = (unsigned short)f2bf(acc[r]);
  } else {
    // ---- per-row s1,s2 = X@wa -> rowdat, pE ----
    int i = (b - 5120) * 4 + wave;
    const float* Xr = X + (size_t)i * F_IN + lane * 8;
    f32x4 x0 = ((const f32x4*)Xr)[0];
    f32x4 x1 = ((const f32x4*)Xr)[1];
    f32x4 w10 = ((const f32x4*)(wa + lane * 8))[0];
    f32x4 w11 = ((const f32x4*)(wa + lane * 8))[1];
    f32x4 w20 = ((const f32x4*)(wa + F_IN + lane * 8))[0];
    f32x4 w21 = ((const f32x4*)(wa + F_IN + lane * 8))[1];
    float d1 = 0.f, d2 = 0.f;
#pragma unroll
    for (int e = 0; e < 4; e++) {
      d1 += x0[e] * w10[e] + x1[e] * w11[e];
      d2 += x0[e] * w20[e] + x1[e] * w21[e];
    }
#pragma unroll
    for (int m = 1; m < 64; m <<= 1) {
      d1 += __shfl_xor(d1, m, 64);
      d2 += __shfl_xor(d2, m, 64);
    }
    if (lane == 0) {
      float s1 = d1, s2 = d2;
      f32x4 rd;
      rd[0] = expf(s1);          // E1
      rd[1] = expf(0.2f * s1);   // E1s
      rd[2] = expf(-s1);         // T1: pos <=> E2 > T1
      rd[3] = 0.f;
      rowdat[i] = rd;
      unsigned e2  = (unsigned)(unsigned short)f2bf(expf(s2));
      unsigned e2s = (unsigned)(unsigned short)f2bf(expf(0.2f * s2));
      pE[i] = (e2s << 16) | e2;
    }
  }
}

// ------- kCompute: 2-stage reg pipeline; wave = 16r x 1024c x 64f ----------
__global__ __launch_bounds__(256, 4) void kCompute(
    const unsigned* __restrict__ mask32, const unsigned short* __restrict__ blob,
    const f32x4* __restrict__ rowdat, const unsigned* __restrict__ pE,
    float* __restrict__ accws, float* __restrict__ denws) {
  int wave = threadIdx.x >> 6, lane = threadIdx.x & 63;
  int lrow = lane & 15, grp = lane >> 4;
  int rb = blockIdx.x >> 3;                 // 0..255 (32-row groups)
  int js = blockIdx.x & 7;                  // col eighth
  int rt01 = wave & 1, fg = wave >> 1;      // rowtile, featgroup(64)
  int row = rb * 32 + rt01 * 16 + lrow;     // P row this lane computes

  f32x4 rd = rowdat[row];
  float E1 = rd[0], E1s = rd[1], T1 = rd[2];

  f32x4 acc[4];
#pragma unroll
  for (int nt = 0; nt < 4; nt++) acc[nt] = (f32x4)(0.0f);
  float dsum = 0.f;

  const unsigned* mrow = mask32 + (size_t)row * (N_NODES / 32) + js * 32;
  const unsigned* pEw = pE + js * 1024 + grp * 8;
  const unsigned short* blobW =
      blob + (((size_t)fg * 4 * 256 + js * 32) * 64 + lane) * 8;

  uint4 P0a, P1a, P0b, P1b;
  s16x8 Ba0, Ba1, Ba2, Ba3, Bb0, Bb1, Bb2, Bb3;

#define LOADP(P0, P1, c)                                              \
  { P0 = *(const uint4*)(pEw + (c) * 32);                             \
    P1 = *(const uint4*)(pEw + (c) * 32 + 4); }
#define LOADB(B0, B1, B2, B3, c)                                      \
  { B0 = *(const s16x8*)(blobW + ((size_t)0 * 256 + (c)) * 512);      \
    B1 = *(const s16x8*)(blobW + ((size_t)1 * 256 + (c)) * 512);      \
    B2 = *(const s16x8*)(blobW + ((size_t)2 * 256 + (c)) * 512);      \
    B3 = *(const s16x8*)(blobW + ((size_t)3 * 256 + (c)) * 512); }
#define PROCE(pw, e)                                                  \
      {                                                               \
        unsigned pu = (pw);                                           \
        float E2  = __builtin_bit_cast(float, pu << 16);              \
        float E2s = __builtin_bit_cast(float, pu & 0xffff0000u);      \
        float sel = (E2 > T1) ? E1 * E2 : E1s * E2s;                  \
        float p = ((b8 >> (e)) & 1u) ? sel : 0.f;                     \
        dsum += p;                                                    \
        af[e] = f2bf(p);                                              \
      }
#define STEP(PA, PB, B0, B1, B2, B3, MW)                              \
  {                                                                   \
    unsigned b8 = ((MW) >> (grp * 8)) & 0xffu;                        \
    s16x8 af;                                                         \
    PROCE(PA.x, 0) PROCE(PA.y, 1) PROCE(PA.z, 2) PROCE(PA.w, 3)       \
    PROCE(PB.x, 4) PROCE(PB.y, 5) PROCE(PB.z, 6) PROCE(PB.w, 7)       \
    acc[0] = __builtin_amdgcn_mfma_f32_16x16x32_bf16(af, B0, acc[0], 0, 0, 0); \
    acc[1] = __builtin_amdgcn_mfma_f32_16x16x32_bf16(af, B1, acc[1], 0, 0, 0); \
    acc[2] = __builtin_amdgcn_mfma_f32_16x16x32_bf16(af, B2, acc[2], 0, 0, 0); \
    acc[3] = __builtin_amdgcn_mfma_f32_16x16x32_bf16(af, B3, acc[3], 0, 0, 0); \
  }

  LOADP(P0a, P1a, 0)
  LOADB(Ba0, Ba1, Ba2, Ba3, 0)

  for (int o = 0; o < 4; o++) {
    uint4 cm0 = *(const uint4*)(mrow + o * 8);
    uint4 cm1 = *(const uint4*)(mrow + o * 8 + 4);
#pragma unroll
    for (int cc = 0; cc < 8; cc += 2) {
      int c = o * 8 + cc;
      unsigned mEven = (cc < 4) ? cm0[cc] : cm1[cc - 4];
      unsigned mOdd  = (cc + 1 < 4) ? cm0[cc + 1] : cm1[cc - 3];
      // even chunk: consume A-regs, prefetch B-regs
      LOADP(P0b, P1b, (c + 1) & 31)
      LOADB(Bb0, Bb1, Bb2, Bb3, (c + 1) & 31)
      STEP(P0a, P1a, Ba0, Ba1, Ba2, Ba3, mEven)
      // odd chunk: consume B-regs, prefetch A-regs
      LOADP(P0a, P1a, (c + 2) & 31)
      LOADB(Ba0, Ba1, Ba2, Ba3, (c + 2) & 31)
      STEP(P0b, P1b, Bb0, Bb1, Bb2, Bb3, mOdd)
    }
  }
#undef STEP
#undef PROCE
#undef LOADB
#undef LOADP

  // den[row]: reduce over the 4 grp groups; fg==0 wave stores
  dsum += __shfl_xor(dsum, 16, 64);
  dsum += __shfl_xor(dsum, 32, 64);
  if (fg == 0 && lane < 16)
    denws[js * N_NODES + rb * 32 + rt01 * 16 + lane] = dsum;

  // acc store: row-in-tile = grp*4+r, feat = fg*64 + nt*16 + lrow
#pragma unroll
  for (int nt = 0; nt < 4; nt++)
#pragma unroll
    for (int r = 0; r < 4; r++)
      accws[((size_t)js * N_NODES + rb * 32 + rt01 * 16 + grp * 4 + r) * F_OUT +
            fg * 64 + nt * 16 + lrow] = acc[nt][r];
}

// ---------------- kD: combine 8 slices, normalize, elu (float4) -----------
__global__ void kD(const float* __restrict__ accws,
                   const float* __restrict__ denws, float* __restrict__ out) {
  int idx4 = blockIdx.x * 256 + threadIdx.x;    // 262144 float4s
  int i = idx4 >> 5;
  const int S4 = N_NODES * F_OUT / 4;
  f32x4 s = (f32x4)(0.0f);
  float d = 0.f;
#pragma unroll
  for (int q = 0; q < JS; q++) {
    s += ((const f32x4*)accws)[idx4 + (size_t)q * S4];
    d += denws[i + q * N_NODES];
  }
  f32x4 v = s / d;
#pragma unroll
  for (int e = 0; e < 4; e++) v[e] = v[e] > 0.f ? v[e] : expm1f(v[e]);
  ((f32x4*)out)[idx4] = v;
}

extern "C" void kernel_launch(void* const* d_in, const int* in_sizes, int n_in,
                              void* d_out, int out_size, void* d_ws, size_t ws_size,
                              hipStream_t stream) {
  const float* X   = (const float*)d_in[0];
  const int*   adj = (const int*)d_in[1];
  const float* W   = (const float*)d_in[2];
  const float* a   = (const float*)d_in[3];
  float* out = (float*)d_out;

  char* ws = (char*)d_ws;
  size_t off = 0;
  unsigned short* WT = (unsigned short*)(ws + off); off += (size_t)F_OUT * F_IN * 2;
  unsigned short* blob = (unsigned short*)(ws + off); off += (size_t)F_OUT * N_NODES * 2;
  f32x4* rowdat = (f32x4*)(ws + off); off += (size_t)N_NODES * 16;
  unsigned* pE = (unsigned*)(ws + off); off += (size_t)N_NODES * 4;
  float* wa = (float*)(ws + off); off += (size_t)2 * F_IN * 4;
  unsigned long long* mask = (unsigned long long*)(ws + off);
  off += (size_t)N_NODES * (N_NODES / 64) * 8;   // 8 MB
  float* accws = (float*)(ws + off); off += (size_t)JS * N_NODES * F_OUT * 4; // 32MB
  float* denws = (float*)(ws + off); off += (size_t)JS * N_NODES * 4;
  (void)in_sizes; (void)n_in; (void)out_size; (void)ws_size;

  kA<<<258, 256, 0, stream>>>(W, a, WT, wa);
  kPrep<<<7168, 256, 0, stream>>>(adj, mask, X, wa, WT, rowdat, pE, blob);
  kCompute<<<(N_NODES / 32) * JS, 256, 0, stream>>>((const unsigned*)mask, blob,
                                                    rowdat, pE, accws, denws);
  kD<<<(N_NODES * F_OUT) / 4 / 256, 256, 0, stream>>>(accws, denws, out);
}

// Round 13
// 457.262 us; speedup vs baseline: 1.2711x; 1.0472x over previous
//
#include <hip/hip_runtime.h>
#include <hip/hip_bf16.h>

// GAT layer, N=8192, F_in=512, F_out=128.
// exp(leaky_relu(s1+s2)) = pos ? exp(s1)exp(s2) : exp(.2 s1)exp(.2 s2)
// r13: kCompute moved to the proven 2-phase LDS schedule (T3-lite):
//  - blob2 layout: per (js, group-of-4-chunks) a CONTIGUOUS 32KB tile
//    [ci 4][ft 8][lane 64][8 shorts] -> staging = 8 linear glds16/thread.
//  - kCompute: block = 64 rows x 1024 cols x 128 feats (wave = 16-row tile,
//    acc[8], no PROCE duplication); dbuf 2x32KB LDS; per group: issue stage
//    of g+1, compute 4 chunks from LDS (ds_read_b128 + MFMA), 1 barrier.
//    B-fragments live in LDS -> ~75 VGPR, no spill; ds latency ~120cy.
//  - kPrep: compute roles dispatched before the mask stream.
// Floor (uncontrollable): ~160us 1GiB ws poison + ~85us input restore.

typedef __attribute__((ext_vector_type(4))) float f32x4;
typedef __attribute__((ext_vector_type(8))) short s16x8;

#define N_NODES 8192
#define F_IN 512
#define F_OUT 128
#define JS 8

static __device__ __forceinline__ short f2bf(float f) {
  __hip_bfloat16 h = __float2bfloat16(f);
  return __builtin_bit_cast(short, h);
}

static __device__ __forceinline__ void glds16(const void* g, void* l) {
  __builtin_amdgcn_global_load_lds(
      (const __attribute__((address_space(1))) unsigned*)g,
      (__attribute__((address_space(3))) unsigned*)l, 16, 0, 0);
}

// ---------------- kA: {W->WT bf16} ∪ {wa = W@a1, W@a2} ----------------
__global__ __launch_bounds__(256) void kA(const float* __restrict__ W,
    const float* __restrict__ a, unsigned short* __restrict__ WT,
    float* __restrict__ wa) {
  int b = blockIdx.x;
  if (b < 256) {
    int idx = b * 256 + threadIdx.x;
    int k = idx >> 7, f = idx & 127;
    WT[(size_t)f * F_IN + k] = (unsigned short)f2bf(W[idx]);
  } else {
    int k = (b - 256) * 256 + threadIdx.x;
    if (k < F_IN) {
      const float* Wr = W + (size_t)k * F_OUT;
      float d1 = 0.f, d2 = 0.f;
#pragma unroll 8
      for (int f = 0; f < F_OUT; f += 4) {
        f32x4 w  = *(const f32x4*)(Wr + f);
        f32x4 a1 = *(const f32x4*)(a + f);
        f32x4 a2 = *(const f32x4*)(a + F_OUT + f);
        d1 += w[0] * a1[0] + w[1] * a1[1] + w[2] * a1[2] + w[3] * a1[3];
        d2 += w[0] * a2[0] + w[1] * a2[1] + w[2] * a2[2] + w[3] * a2[3];
      }
      wa[k] = d1;
      wa[F_IN + k] = d2;
    }
  }
}

// ---- kPrep: {h GEMM -> blob2} ∪ {rowdat/pE} ∪ {adj->mask (streams last)} --
// blob2 short index: (((((js*8+g)*4+ci)*8+ft)*64)+l)*8+e where the value is
// h[ft*16 + (l&15)][((js*32+g*4+ci)*32) + (l>>4)*8 + e].
__global__ __launch_bounds__(256) void kPrep(const int* __restrict__ adj,
    unsigned long long* __restrict__ mask, const float* __restrict__ X,
    const float* __restrict__ wa, const unsigned short* __restrict__ WT,
    f32x4* __restrict__ rowdat, unsigned* __restrict__ pE,
    unsigned short* __restrict__ blob2) {
  int b = blockIdx.x;
  int wave = threadIdx.x >> 6, lane = threadIdx.x & 63;

  if (b < 1024) {
    // ---- h GEMM tile -> blob2 (group-contiguous fragment layout) ----
    int lrow = lane & 15, grp = lane >> 4;
    int tile = b * 4 + wave;                       // 4096 tiles
    int fb = tile & 7;
    int nb = tile >> 3;
    const unsigned short* Ar = WT + (size_t)(fb * 16 + lrow) * F_IN + grp * 8;
    const float* Br = X + (size_t)(nb * 16 + lrow) * F_IN + grp * 8;

    f32x4 acc = (f32x4)(0.0f);
#pragma unroll
    for (int k0 = 0; k0 < F_IN; k0 += 32) {
      s16x8 af = *(const s16x8*)(Ar + k0);
      f32x4 b0 = *(const f32x4*)(Br + k0);
      f32x4 b1 = *(const f32x4*)(Br + k0 + 4);
      s16x8 bf;
#pragma unroll
      for (int e = 0; e < 4; e++) { bf[e] = f2bf(b0[e]); bf[e + 4] = f2bf(b1[e]); }
      acc = __builtin_amdgcn_mfma_f32_16x16x32_bf16(af, bf, acc, 0, 0, 0);
    }
    // acc[r] = h[f = fb*16+grp*4+r][c = nb*16+lrow] -> blob2 scatter
    int c = nb * 16 + lrow;
    int jsx = c >> 10;
    int ctj = (c >> 5) & 31;
    int g = ctj >> 2, ci = ctj & 3;
    int cpos = c & 31;
    int e = cpos & 7;
    int lbase = (cpos >> 3) << 4;
    size_t tbase = ((((size_t)jsx * 8 + g) * 4 + ci) * 8 + fb) * 64;
#pragma unroll
    for (int r = 0; r < 4; r++) {
      int l = lbase + grp * 4 + r;
      blob2[(tbase + l) * 8 + e] = (unsigned short)f2bf(acc[r]);
    }
  } else if (b < 3072) {
    // ---- per-row s1,s2 = X@wa -> rowdat, pE ----
    int i = (b - 1024) * 4 + wave;
    const float* Xr = X + (size_t)i * F_IN + lane * 8;
    f32x4 x0 = ((const f32x4*)Xr)[0];
    f32x4 x1 = ((const f32x4*)Xr)[1];
    f32x4 w10 = ((const f32x4*)(wa + lane * 8))[0];
    f32x4 w11 = ((const f32x4*)(wa + lane * 8))[1];
    f32x4 w20 = ((const f32x4*)(wa + F_IN + lane * 8))[0];
    f32x4 w21 = ((const f32x4*)(wa + F_IN + lane * 8))[1];
    float d1 = 0.f, d2 = 0.f;
#pragma unroll
    for (int e = 0; e < 4; e++) {
      d1 += x0[e] * w10[e] + x1[e] * w11[e];
      d2 += x0[e] * w20[e] + x1[e] * w21[e];
    }
#pragma unroll
    for (int m = 1; m < 64; m <<= 1) {
      d1 += __shfl_xor(d1, m, 64);
      d2 += __shfl_xor(d2, m, 64);
    }
    if (lane == 0) {
      float s1 = d1, s2 = d2;
      f32x4 rd;
      rd[0] = expf(s1);          // E1
      rd[1] = expf(0.2f * s1);   // E1s
      rd[2] = expf(-s1);         // T1: pos <=> E2 > T1
      rd[3] = 0.f;
      rowdat[i] = rd;
      unsigned e2  = (unsigned)(unsigned short)f2bf(expf(s2));
      unsigned e2s = (unsigned)(unsigned short)f2bf(expf(0.2f * s2));
      pE[i] = (e2s << 16) | e2;
    }
  } else {
    // ---- adj -> bitmask; 256 cols (4 ballots + 32B store) per task ----
    const int nwaves = 4096 * 4;
    int wid = (b - 3072) * 4 + wave;
    const int ntasks = N_NODES * (N_NODES / 256);   // 262,144
    for (int task = wid; task < ntasks; task += nwaves) {
      int row = task >> 5;
      int cg = task & 31;
      const int* p = adj + (size_t)row * N_NODES + cg * 256 + lane;
      int v0 = p[0], v1 = p[64], v2 = p[128], v3 = p[192];
      unsigned long long b0 = __ballot(v0 != 0);
      unsigned long long b1 = __ballot(v1 != 0);
      unsigned long long b2 = __ballot(v2 != 0);
      unsigned long long b3 = __ballot(v3 != 0);
      if (lane == 0) {
        unsigned long long* q = mask + (size_t)row * (N_NODES / 64) + cg * 4;
        ulonglong2 w0; w0.x = b0; w0.y = b1;
        ulonglong2 w1; w1.x = b2; w1.y = b3;
        *(ulonglong2*)(q) = w0;
        *(ulonglong2*)(q + 2) = w1;
      }
    }
  }
}

// ------- kCompute: 2-phase LDS pipeline; block = 64r x 1024c x 128f --------
__global__ __launch_bounds__(256, 4) void kCompute(
    const unsigned* __restrict__ mask32, const unsigned short* __restrict__ blob2,
    const f32x4* __restrict__ rowdat, const unsigned* __restrict__ pE,
    float* __restrict__ accws, float* __restrict__ denws) {
  __shared__ char lds[2][32768];
  int tid = threadIdx.x;
  int wave = tid >> 6, lane = tid & 63;
  int lrow = lane & 15, grp = lane >> 4;
  int rb = blockIdx.x >> 3;                 // 0..127 (64-row groups)
  int js = blockIdx.x & 7;                  // col eighth (32 chunks)
  int row = rb * 64 + wave * 16 + lrow;     // P row this lane computes

  f32x4 rd = rowdat[row];
  float E1 = rd[0], E1s = rd[1], T1 = rd[2];

  f32x4 acc[8];
#pragma unroll
  for (int nt = 0; nt < 8; nt++) acc[nt] = (f32x4)(0.0f);
  float dsum = 0.f;

  const unsigned* mrow = mask32 + (size_t)row * (N_NODES / 32) + js * 32;
  const char* gbase = (const char*)blob2 + (size_t)js * 8 * 32768;

  // prologue: stage group 0
#pragma unroll
  for (int r = 0; r < 8; r++)
    glds16(gbase + r * 4096 + tid * 16, &lds[0][r * 4096 + tid * 16]);
  __syncthreads();

  int cur = 0;
  for (int g = 0; g < 8; g++) {
    if (g < 7) {
      const char* gsrc = gbase + (size_t)(g + 1) * 32768;
      char* ldst = &lds[cur ^ 1][0];
#pragma unroll
      for (int r = 0; r < 8; r++)
        glds16(gsrc + r * 4096 + tid * 16, ldst + r * 4096 + tid * 16);
    }
    uint4 mm = *(const uint4*)(mrow + g * 4);
#pragma unroll
    for (int ci = 0; ci < 4; ci++) {
      int j0 = (js * 32 + g * 4 + ci) * 32 + grp * 8;
      uint4 P0 = *(const uint4*)(pE + j0);
      uint4 P1 = *(const uint4*)(pE + j0 + 4);
      unsigned b8 = (mm[ci] >> (grp * 8)) & 0xffu;
      s16x8 af;
#define PROCE(pw, e)                                                  \
      {                                                               \
        unsigned pu = (pw);                                           \
        float E2  = __builtin_bit_cast(float, pu << 16);              \
        float E2s = __builtin_bit_cast(float, pu & 0xffff0000u);      \
        float sel = (E2 > T1) ? E1 * E2 : E1s * E2s;                  \
        float p = ((b8 >> (e)) & 1u) ? sel : 0.f;                     \
        dsum += p;                                                    \
        af[e] = f2bf(p);                                              \
      }
      PROCE(P0.x, 0) PROCE(P0.y, 1) PROCE(P0.z, 2) PROCE(P0.w, 3)
      PROCE(P1.x, 4) PROCE(P1.y, 5) PROCE(P1.z, 6) PROCE(P1.w, 7)
#undef PROCE
#pragma unroll
      for (int nt = 0; nt < 8; nt++) {
        s16x8 bf = *(const s16x8*)(&lds[cur][(ci * 8 + nt) * 1024 + lane * 16]);
        acc[nt] = __builtin_amdgcn_mfma_f32_16x16x32_bf16(af, bf, acc[nt], 0, 0, 0);
      }
    }
    __syncthreads();    // drains stage of g+1; protects lds[cur] for reuse
    cur ^= 1;
  }

  // den[row]: reduce over the 4 grp groups (lanes l, l^16, l^32, l^48)
  dsum += __shfl_xor(dsum, 16, 64);
  dsum += __shfl_xor(dsum, 32, 64);
  if (lane < 16)
    denws[js * N_NODES + rb * 64 + wave * 16 + lane] = dsum;

  // acc store: D row within row-tile = grp*4+r, feat = nt*16 + lrow
#pragma unroll
  for (int nt = 0; nt < 8; nt++)
#pragma unroll
    for (int r = 0; r < 4; r++)
      accws[((size_t)js * N_NODES + rb * 64 + wave * 16 + grp * 4 + r) * F_OUT +
            nt * 16 + lrow] = acc[nt][r];
}

// ---------------- kD: combine 8 slices, normalize, elu (float4) -----------
__global__ void kD(const float* __restrict__ accws,
                   const float* __restrict__ denws, float* __restrict__ out) {
  int idx4 = blockIdx.x * 256 + threadIdx.x;    // 262144 float4s
  int i = idx4 >> 5;
  const int S4 = N_NODES * F_OUT / 4;
  f32x4 s = (f32x4)(0.0f);
  float d = 0.f;
#pragma unroll
  for (int q = 0; q < JS; q++) {
    s += ((const f32x4*)accws)[idx4 + (size_t)q * S4];
    d += denws[i + q * N_NODES];
  }
  f32x4 v = s / d;
#pragma unroll
  for (int e = 0; e < 4; e++) v[e] = v[e] > 0.f ? v[e] : expm1f(v[e]);
  ((f32x4*)out)[idx4] = v;
}

extern "C" void kernel_launch(void* const* d_in, const int* in_sizes, int n_in,
                              void* d_out, int out_size, void* d_ws, size_t ws_size,
                              hipStream_t stream) {
  const float* X   = (const float*)d_in[0];
  const int*   adj = (const int*)d_in[1];
  const float* W   = (const float*)d_in[2];
  const float* a   = (const float*)d_in[3];
  float* out = (float*)d_out;

  char* ws = (char*)d_ws;
  size_t off = 0;
  unsigned short* WT = (unsigned short*)(ws + off); off += (size_t)F_OUT * F_IN * 2;
  unsigned short* blob2 = (unsigned short*)(ws + off); off += (size_t)F_OUT * N_NODES * 2;
  f32x4* rowdat = (f32x4*)(ws + off); off += (size_t)N_NODES * 16;
  unsigned* pE = (unsigned*)(ws + off); off += (size_t)N_NODES * 4;
  float* wa = (float*)(ws + off); off += (size_t)2 * F_IN * 4;
  unsigned long long* mask = (unsigned long long*)(ws + off);
  off += (size_t)N_NODES * (N_NODES / 64) * 8;   // 8 MB
  float* accws = (float*)(ws + off); off += (size_t)JS * N_NODES * F_OUT * 4; // 32MB
  float* denws = (float*)(ws + off); off += (size_t)JS * N_NODES * 4;
  (void)in_sizes; (void)n_in; (void)out_size; (void)ws_size;

  kA<<<258, 256, 0, stream>>>(W, a, WT, wa);
  kPrep<<<7168, 256, 0, stream>>>(adj, mask, X, wa, WT, rowdat, pE, blob2);
  kCompute<<<(N_NODES / 64) * JS, 256, 0, stream>>>((const unsigned*)mask, blob2,
                                                    rowdat, pE, accws, denws);
  kD<<<(N_NODES * F_OUT) / 4 / 256, 256, 0, stream>>>(accws, denws, out);
}